// Round 9
// baseline (105.698 us; speedup 1.0000x reference)
//
#include <hip/hip_runtime.h>
#include <math.h>

namespace {

typedef float vf4 __attribute__((ext_vector_type(4)));

constexpr int kRowBytes = 64 * 1024 * 4;  // 262144: one image row (W*C*4)
constexpr int kColBytes = 1024 * 4;       // 4096: one pixel (C*4)

__device__ __forceinline__ int rfl(int x) { return __builtin_amdgcn_readfirstlane(x); }

__device__ __forceinline__ vf4 splat4(float x) {
  vf4 v = {x, x, x, x};
  return v;
}

// ---------------------------------------------------------------------------
// Sort: deterministic bitonic sort of the N rois by quantized y-center.
// One block, 512 threads, LDS-resident. perm[sorted_slot] = original index.
// XCD-chunked dispatch then gives each XCD a contiguous y-band that fits
// its 4 MB L2 (random roi order thrashes it: image is 13 MB).
// ---------------------------------------------------------------------------
__global__ __launch_bounds__(512) void roi_sort_kernel(
    const float* __restrict__ rois, const int* __restrict__ stride_p,
    int* __restrict__ perm, int N) {
  __shared__ unsigned sk[1024];
  const int tid = threadIdx.x;
  const float s = (float)(*stride_p);

  for (int i = tid; i < 1024; i += 512) {
    unsigned key = 0xFFFFFFFFu;
    if (i < N) {
      const float yc = (rois[i * 4 + 0] + rois[i * 4 + 2]) * 0.5f / s;  // rows
      int q = (int)(yc * (1024.0f / 50.0f));
      q = min(max(q, 0), 1023);
      key = ((unsigned)q << 10) | (unsigned)i;  // composite -> deterministic
    }
    sk[i] = key;
  }
  __syncthreads();

  for (unsigned k = 2; k <= 1024; k <<= 1) {
    for (unsigned j = k >> 1; j > 0; j >>= 1) {
      const unsigned t = tid;  // 512 compare pairs
      const unsigned i1 = ((t & ~(j - 1)) << 1) | (t & (j - 1));
      const unsigned i2 = i1 | j;
      const unsigned a = sk[i1], b = sk[i2];
      const bool up = ((i1 & k) == 0);
      if ((a > b) == up) { sk[i1] = b; sk[i2] = a; }
      __syncthreads();
    }
  }

  for (int i = tid; i < N; i += 512) perm[i] = (int)(sk[i] & 1023u);
}

// ---------------------------------------------------------------------------
// Setup: one thread per (sorted_slot, k). Tables in SORTED order; all
// divisions/floors/clamps/validity-folding happen here once.
//   y entry t=(sn*7+py): tab[2t] = row byte offsets, tab[2t+1] = y-weights
//   x entry t=(sn*7+px): tab[N*14+2t], tab[N*14+2t+1]
// ---------------------------------------------------------------------------
__global__ void roi_setup_kernel(const float* __restrict__ rois,
                                 const int* __restrict__ stride_p,
                                 const int* __restrict__ perm,
                                 int4* __restrict__ tab, int N) {
  const int t = blockIdx.x * 64 + threadIdx.x;
  if (t >= N * 7) return;
  const int sn = t / 7;
  const int k = t - sn * 7;
  const int n = perm[sn];

  const float s = (float)(*stride_p);
  // boxes = (rois / stride) / [H, W, H, W] -- mirror reference op order
  const float by1 = rois[n * 4 + 0] / s / 50.0f;
  const float bx1 = rois[n * 4 + 1] / s / 64.0f;
  const float by2 = rois[n * 4 + 2] / s / 50.0f;
  const float bx2 = rois[n * 4 + 3] / s / 64.0f;
  const float stepy = (by2 - by1) * 49.0f / 13.0f;
  const float stepx = (bx2 - bx1) * 63.0f / 13.0f;

  const float ys0 = by1 * 49.0f + (float)(2 * k + 0) * stepy;
  const float ys1 = by1 * 49.0f + (float)(2 * k + 1) * stepy;
  const float vy0 = (ys0 >= 0.0f && ys0 <= 49.0f) ? 1.0f : 0.0f;
  const float vy1 = (ys1 >= 0.0f && ys1 <= 49.0f) ? 1.0f : 0.0f;
  const float yf0 = floorf(ys0), yf1 = floorf(ys1);
  const float wy0 = ys0 - yf0, wy1 = ys1 - yf1;
  const int r0 = min(max((int)yf0, 0), 49);
  const int r1 = min(r0 + 1, 49);
  const int r2 = min(max((int)yf1, 0), 49);
  const int r3 = min(r2 + 1, 49);
  tab[2 * t] = make_int4(r0 * kRowBytes, r1 * kRowBytes,
                         r2 * kRowBytes, r3 * kRowBytes);
  ((float4*)tab)[2 * t + 1] =
      make_float4((1.0f - wy0) * vy0, wy0 * vy0, (1.0f - wy1) * vy1, wy1 * vy1);

  const float xs0 = bx1 * 63.0f + (float)(2 * k + 0) * stepx;
  const float xs1 = bx1 * 63.0f + (float)(2 * k + 1) * stepx;
  const float vx0 = (xs0 >= 0.0f && xs0 <= 63.0f) ? 1.0f : 0.0f;
  const float vx1 = (xs1 >= 0.0f && xs1 <= 63.0f) ? 1.0f : 0.0f;
  const float xf0 = floorf(xs0), xf1 = floorf(xs1);
  const float wx0 = xs0 - xf0, wx1 = xs1 - xf1;
  const int c0 = min(max((int)xf0, 0), 63);
  const int c1 = min(c0 + 1, 63);
  const int c2 = min(max((int)xf1, 0), 63);
  const int c3 = min(c2 + 1, 63);
  const int xoff = N * 14;
  tab[xoff + 2 * t] = make_int4(c0 * kColBytes, c1 * kColBytes,
                                c2 * kColBytes, c3 * kColBytes);
  ((float4*)tab)[xoff + 2 * t + 1] =
      make_float4((1.0f - wx0) * vx0, wx0 * vx0, (1.0f - wx1) * vx1, wx1 * vx1);
}

// ---------------------------------------------------------------------------
// Main: one block per (sorted roi, py, channel-half). 896 threads = 14
// waves; px = tid>>7 (2 waves per px), c4 = half*128 + (tid&127). Waves are
// independent one-shot (no loop, no syncthreads); consecutive-px waves on
// the SAME CU touch overlapping cells -> L1 temporal hits replace L2
// traffic (stepx ~= 1 cell on average, so ~1/3 of cells are shared).
// ---------------------------------------------------------------------------
__global__ __launch_bounds__(896) void roi_pool_tab(
    const float* __restrict__ img,
    const int4* __restrict__ tab,
    const int* __restrict__ perm, int N,
    float* __restrict__ out) {
  const int bid = blockIdx.x;
  // XCD-chunked swizzle (bijective when gridDim % 8 == 0): each XCD gets a
  // contiguous run of SORTED (roi,py,half) groups -> compact y-band in L2.
  const int chunk = gridDim.x >> 3;
  const int pos = ((gridDim.x & 7) == 0) ? ((bid & 7) * chunk + (bid >> 3)) : bid;
  const int sn   = pos / 14;           // sorted roi
  const int rem  = pos - sn * 14;
  const int py   = rem >> 1;
  const int half = rem & 1;
  const int px = threadIdx.x >> 7;               // 0..6, wave-uniform
  const int c4 = half * 128 + (threadIdx.x & 127);  // float4 channel index

  const int yt = 2 * (sn * 7 + py);
  const int xt = N * 14 + 2 * (sn * 7 + px);
  const int    n  = perm[sn];          // original roi (output addressing)
  const int4   yi = tab[yt];
  const float4 yw = ((const float4*)tab)[yt + 1];
  const int4   xi = tab[xt];
  const float4 xw = ((const float4*)tab)[xt + 1];

  // force offsets into SGPRs (scalar base folding for the gathers)
  const int r0 = rfl(yi.x), r1 = rfl(yi.y), r2 = rfl(yi.z), r3 = rfl(yi.w);
  const int c0 = rfl(xi.x), c1 = rfl(xi.y), c2 = rfl(xi.z), c3 = rfl(xi.w);

  const vf4 gy0 = splat4(yw.x), fy0 = splat4(yw.y);
  const vf4 gy1 = splat4(yw.z), fy1 = splat4(yw.w);
  const vf4 gx0 = splat4(xw.x), fx0 = splat4(xw.y);
  const vf4 gx1 = splat4(xw.z), fx1 = splat4(xw.w);

  const char* __restrict__ imgb = (const char*)img;
  const int coff = c4 * 16;  // shared per-lane voffset

  // uniform dedup conditions (exact byte-offset equality)
  const bool c2e0 = (c2 == c0), c2e1 = (c2 == c1);
  const bool c3e1 = (c3 == c1), c3e2 = (c3 == c2);

  auto rowblend = [&](int rB, vf4& b0, vf4& b1) {
    const vf4 q0 = *(const vf4*)(imgb + (rB + c0) + coff);
    const vf4 q1 = *(const vf4*)(imgb + (rB + c1) + coff);
    vf4 q2, q3;
    if (c2e0)      q2 = q0;
    else if (c2e1) q2 = q1;
    else           q2 = *(const vf4*)(imgb + (rB + c2) + coff);
    if (c3e1)      q3 = q1;
    else if (c3e2) q3 = q2;
    else           q3 = *(const vf4*)(imgb + (rB + c3) + coff);
    b0 = q0 * gx0 + q1 * fx0;
    b1 = q2 * gx1 + q3 * fx1;
  };

  vf4 b00, b01, b10, b11, b20, b21, b30, b31;
  rowblend(r0, b00, b01);
  if (r1 == r0) { b10 = b00; b11 = b01; }
  else rowblend(r1, b10, b11);
  if (r2 == r0)      { b20 = b00; b21 = b01; }
  else if (r2 == r1) { b20 = b10; b21 = b11; }
  else rowblend(r2, b20, b21);
  if (r3 == r1)      { b30 = b10; b31 = b11; }
  else if (r3 == r2) { b30 = b20; b31 = b21; }
  else rowblend(r3, b30, b31);

  vf4 m = b00 * gy0 + b10 * fy0;
  vf4 v = b01 * gy0 + b11 * fy0;
  m = __builtin_elementwise_max(m, v);
  v = b20 * gy1 + b30 * fy1;
  m = __builtin_elementwise_max(m, v);
  v = b21 * gy1 + b31 * fy1;
  m = __builtin_elementwise_max(m, v);

  __builtin_nontemporal_store(
      m, (vf4*)out + ((size_t)n * 49 + py * 7 + px) * 256 + c4);
}

// ---------------------------------------------------------------------------
// Fallback (R6 kernel, self-contained): used only if ws_size is too small.
// ---------------------------------------------------------------------------
__device__ __forceinline__ float rflf(float x) {
  union { float f; int i; } u;
  u.f = x;
  u.i = __builtin_amdgcn_readfirstlane(u.i);
  return u.f;
}

__global__ __launch_bounds__(256) void roi_pool_kernel(
    const float* __restrict__ img, const float* __restrict__ rois,
    const int* __restrict__ stride_p, float* __restrict__ out) {
  const int bid = blockIdx.x;
  const int chunk = gridDim.x >> 3;
  const int pos = ((gridDim.x & 7) == 0) ? ((bid & 7) * chunk + (bid >> 3)) : bid;
  const int n  = pos / 49;
  const int rr = pos - n * 49;
  const int py = rr / 7;
  const int px = rr - py * 7;
  const int c4 = threadIdx.x;

  const float s = (float)(*stride_p);
  const float by1 = rois[n * 4 + 0] / s / 50.0f;
  const float bx1 = rois[n * 4 + 1] / s / 64.0f;
  const float by2 = rois[n * 4 + 2] / s / 50.0f;
  const float bx2 = rois[n * 4 + 3] / s / 64.0f;
  const float stepy = (by2 - by1) * 49.0f / 13.0f;
  const float stepx = (bx2 - bx1) * 63.0f / 13.0f;

  const float ys0 = by1 * 49.0f + (float)(2 * py + 0) * stepy;
  const float ys1 = by1 * 49.0f + (float)(2 * py + 1) * stepy;
  const float xs0 = bx1 * 63.0f + (float)(2 * px + 0) * stepx;
  const float xs1 = bx1 * 63.0f + (float)(2 * px + 1) * stepx;
  const float vy0 = (ys0 >= 0.0f && ys0 <= 49.0f) ? 1.0f : 0.0f;
  const float vy1 = (ys1 >= 0.0f && ys1 <= 49.0f) ? 1.0f : 0.0f;
  const float vx0 = (xs0 >= 0.0f && xs0 <= 63.0f) ? 1.0f : 0.0f;
  const float vx1 = (xs1 >= 0.0f && xs1 <= 63.0f) ? 1.0f : 0.0f;
  const float yf0 = floorf(ys0), yf1 = floorf(ys1);
  const float xf0 = floorf(xs0), xf1 = floorf(xs1);
  const float wy0 = ys0 - yf0, wy1 = ys1 - yf1;
  const float wx0 = xs0 - xf0, wx1 = xs1 - xf1;
  const int r0i = min(max((int)yf0, 0), 49);
  const int r2i = min(max((int)yf1, 0), 49);
  const int c0i = min(max((int)xf0, 0), 63);
  const int c2i = min(max((int)xf1, 0), 63);
  const int r0 = rfl(r0i), r1 = rfl(min(r0i + 1, 49));
  const int r2 = rfl(r2i), r3 = rfl(min(r2i + 1, 49));
  const int c0 = rfl(c0i), c1 = rfl(min(c0i + 1, 63));
  const int c2 = rfl(c2i), c3 = rfl(min(c2i + 1, 63));
  const vf4 gy0 = splat4(rflf((1.0f - wy0) * vy0));
  const vf4 fy0 = splat4(rflf(wy0 * vy0));
  const vf4 gy1 = splat4(rflf((1.0f - wy1) * vy1));
  const vf4 fy1 = splat4(rflf(wy1 * vy1));
  const vf4 gx0 = splat4(rflf((1.0f - wx0) * vx0));
  const vf4 fx0 = splat4(rflf(wx0 * vx0));
  const vf4 gx1 = splat4(rflf((1.0f - wx1) * vx1));
  const vf4 fx1 = splat4(rflf(wx1 * vx1));

  const vf4* __restrict__ img4 = (const vf4*)img;
  const bool c2e0 = (c2 == c0), c2e1 = (c2 == c1);
  const bool c3e1 = (c3 == c1), c3e2 = (c3 == c2);
  const int co0 = c0 * 256, co1 = c1 * 256, co2 = c2 * 256, co3 = c3 * 256;

  auto rowblend = [&](int r, vf4& b0, vf4& b1) {
    const vf4* rp = img4 + r * (64 * 256);
    const vf4 q0 = rp[co0 + c4];
    const vf4 q1 = rp[co1 + c4];
    vf4 q2, q3;
    if (c2e0)      q2 = q0;
    else if (c2e1) q2 = q1;
    else           q2 = rp[co2 + c4];
    if (c3e1)      q3 = q1;
    else if (c3e2) q3 = q2;
    else           q3 = rp[co3 + c4];
    b0 = q0 * gx0 + q1 * fx0;
    b1 = q2 * gx1 + q3 * fx1;
  };

  vf4 b00, b01, b10, b11, b20, b21, b30, b31;
  rowblend(r0, b00, b01);
  if (r1 == r0) { b10 = b00; b11 = b01; }
  else rowblend(r1, b10, b11);
  if (r2 == r0)      { b20 = b00; b21 = b01; }
  else if (r2 == r1) { b20 = b10; b21 = b11; }
  else rowblend(r2, b20, b21);
  if (r3 == r1)      { b30 = b10; b31 = b11; }
  else if (r3 == r2) { b30 = b20; b31 = b21; }
  else rowblend(r3, b30, b31);

  vf4 m = b00 * gy0 + b10 * fy0;
  vf4 v = b01 * gy0 + b11 * fy0;
  m = __builtin_elementwise_max(m, v);
  v = b20 * gy1 + b30 * fy1;
  m = __builtin_elementwise_max(m, v);
  v = b21 * gy1 + b31 * fy1;
  m = __builtin_elementwise_max(m, v);

  __builtin_nontemporal_store(m, (vf4*)out + (size_t)pos * 256 + c4);
}

}  // namespace

extern "C" void kernel_launch(void* const* d_in, const int* in_sizes, int n_in,
                              void* d_out, int out_size, void* d_ws, size_t ws_size,
                              hipStream_t stream) {
  const float* img      = (const float*)d_in[0];
  const float* rois     = (const float*)d_in[1];
  const int*   stride_p = (const int*)d_in[2];
  float*       out      = (float*)d_out;

  const int N = in_sizes[1] / 4;                     // 1000
  const size_t tab_bytes  = (size_t)N * 28 * 16;     // 28 int4s per roi
  const size_t perm_bytes = (size_t)((N + 63) & ~63) * sizeof(int);

  if (ws_size >= tab_bytes + perm_bytes && N <= 1024) {
    int4* tab  = (int4*)d_ws;
    int*  perm = (int*)((char*)d_ws + tab_bytes);
    roi_sort_kernel<<<1, 512, 0, stream>>>(rois, stride_p, perm, N);
    roi_setup_kernel<<<(N * 7 + 63) / 64, 64, 0, stream>>>(rois, stride_p, perm,
                                                           tab, N);
    roi_pool_tab<<<N * 14, 896, 0, stream>>>(img, tab, perm, N, out);
  } else {
    roi_pool_kernel<<<N * 49, 256, 0, stream>>>(img, rois, stride_p, out);
  }
}

// Round 10
// 86.242 us; speedup vs baseline: 1.2256x; 1.2256x over previous
//
#include <hip/hip_runtime.h>
#include <math.h>

namespace {

typedef float vf4 __attribute__((ext_vector_type(4)));

constexpr int kRowBytes = 64 * 1024 * 4;  // 262144: one image row (W*C*4)
constexpr int kColBytes = 1024 * 4;       // 4096: one pixel (C*4)

__device__ __forceinline__ int rfl(int x) { return __builtin_amdgcn_readfirstlane(x); }

__device__ __forceinline__ vf4 splat4(float x) {
  vf4 v = {x, x, x, x};
  return v;
}

// ---------------------------------------------------------------------------
// Sort: deterministic bitonic sort of the N rois by quantized y-center.
// One block, 512 threads, LDS-resident. perm[sorted_slot] = original index.
// XCD-chunked dispatch then gives each XCD a contiguous y-band that fits
// its 4 MB L2 (random roi order thrashes it: image is 13 MB).
// R9 verified: FETCH_SIZE 245 MB -> 41 MB with this in place.
// ---------------------------------------------------------------------------
__global__ __launch_bounds__(512) void roi_sort_kernel(
    const float* __restrict__ rois, const int* __restrict__ stride_p,
    int* __restrict__ perm, int N) {
  __shared__ unsigned sk[1024];
  const int tid = threadIdx.x;
  const float s = (float)(*stride_p);

  for (int i = tid; i < 1024; i += 512) {
    unsigned key = 0xFFFFFFFFu;
    if (i < N) {
      const float yc = (rois[i * 4 + 0] + rois[i * 4 + 2]) * 0.5f / s;  // rows
      int q = (int)(yc * (1024.0f / 50.0f));
      q = min(max(q, 0), 1023);
      key = ((unsigned)q << 10) | (unsigned)i;  // composite -> deterministic
    }
    sk[i] = key;
  }
  __syncthreads();

  for (unsigned k = 2; k <= 1024; k <<= 1) {
    for (unsigned j = k >> 1; j > 0; j >>= 1) {
      const unsigned t = tid;  // 512 compare pairs
      const unsigned i1 = ((t & ~(j - 1)) << 1) | (t & (j - 1));
      const unsigned i2 = i1 | j;
      const unsigned a = sk[i1], b = sk[i2];
      const bool up = ((i1 & k) == 0);
      if ((a > b) == up) { sk[i1] = b; sk[i2] = a; }
      __syncthreads();
    }
  }

  for (int i = tid; i < N; i += 512) perm[i] = (int)(sk[i] & 1023u);
}

// ---------------------------------------------------------------------------
// Setup: one thread per (sorted_slot, k). Tables in SORTED order; all
// divisions/floors/clamps/validity-folding happen here once (R7: -8 us of
// per-wave VALU vs recomputing in the main kernel).
//   y entry t=(sn*7+py): tab[2t] = row byte offsets, tab[2t+1] = y-weights
//   x entry t=(sn*7+px): tab[N*14+2t], tab[N*14+2t+1]
// ---------------------------------------------------------------------------
__global__ void roi_setup_kernel(const float* __restrict__ rois,
                                 const int* __restrict__ stride_p,
                                 const int* __restrict__ perm,
                                 int4* __restrict__ tab, int N) {
  const int t = blockIdx.x * 64 + threadIdx.x;
  if (t >= N * 7) return;
  const int sn = t / 7;
  const int k = t - sn * 7;
  const int n = perm[sn];

  const float s = (float)(*stride_p);
  // boxes = (rois / stride) / [H, W, H, W] -- mirror reference op order
  const float by1 = rois[n * 4 + 0] / s / 50.0f;
  const float bx1 = rois[n * 4 + 1] / s / 64.0f;
  const float by2 = rois[n * 4 + 2] / s / 50.0f;
  const float bx2 = rois[n * 4 + 3] / s / 64.0f;
  const float stepy = (by2 - by1) * 49.0f / 13.0f;
  const float stepx = (bx2 - bx1) * 63.0f / 13.0f;

  const float ys0 = by1 * 49.0f + (float)(2 * k + 0) * stepy;
  const float ys1 = by1 * 49.0f + (float)(2 * k + 1) * stepy;
  const float vy0 = (ys0 >= 0.0f && ys0 <= 49.0f) ? 1.0f : 0.0f;
  const float vy1 = (ys1 >= 0.0f && ys1 <= 49.0f) ? 1.0f : 0.0f;
  const float yf0 = floorf(ys0), yf1 = floorf(ys1);
  const float wy0 = ys0 - yf0, wy1 = ys1 - yf1;
  const int r0 = min(max((int)yf0, 0), 49);
  const int r1 = min(r0 + 1, 49);
  const int r2 = min(max((int)yf1, 0), 49);
  const int r3 = min(r2 + 1, 49);
  tab[2 * t] = make_int4(r0 * kRowBytes, r1 * kRowBytes,
                         r2 * kRowBytes, r3 * kRowBytes);
  ((float4*)tab)[2 * t + 1] =
      make_float4((1.0f - wy0) * vy0, wy0 * vy0, (1.0f - wy1) * vy1, wy1 * vy1);

  const float xs0 = bx1 * 63.0f + (float)(2 * k + 0) * stepx;
  const float xs1 = bx1 * 63.0f + (float)(2 * k + 1) * stepx;
  const float vx0 = (xs0 >= 0.0f && xs0 <= 63.0f) ? 1.0f : 0.0f;
  const float vx1 = (xs1 >= 0.0f && xs1 <= 63.0f) ? 1.0f : 0.0f;
  const float xf0 = floorf(xs0), xf1 = floorf(xs1);
  const float wx0 = xs0 - xf0, wx1 = xs1 - xf1;
  const int c0 = min(max((int)xf0, 0), 63);
  const int c1 = min(c0 + 1, 63);
  const int c2 = min(max((int)xf1, 0), 63);
  const int c3 = min(c2 + 1, 63);
  const int xoff = N * 14;
  tab[xoff + 2 * t] = make_int4(c0 * kColBytes, c1 * kColBytes,
                                c2 * kColBytes, c3 * kColBytes);
  ((float4*)tab)[xoff + 2 * t + 1] =
      make_float4((1.0f - wx0) * vx0, wx0 * vx0, (1.0f - wx1) * vx1, wx1 * vx1);
}

// ---------------------------------------------------------------------------
// Main (R8 structure, best verified: 86.4 us): one block of 256 threads per
// SORTED output position. Per wave: 2 uniform table loads, 8 readfirstlanes,
// ~10 deduped gathers (uniform SGPR base + shared c4*16 voffset), ~35 packed
// blends, 1 NT store to the ORIGINAL roi's output slice. 256-thread blocks
// keep 8 blocks/CU resident (R9: 896-thread blocks drop to 1/CU -> -20 us).
// ---------------------------------------------------------------------------
__global__ __launch_bounds__(256) void roi_pool_tab(
    const float* __restrict__ img,
    const int4* __restrict__ tab,
    const int* __restrict__ perm, int N,
    float* __restrict__ out) {
  const int bid = blockIdx.x;
  // XCD-chunked swizzle (bijective when gridDim % 8 == 0): each XCD gets a
  // contiguous run of SORTED positions -> a compact y-band in its L2.
  const int chunk = gridDim.x >> 3;
  const int pos = ((gridDim.x & 7) == 0) ? ((bid & 7) * chunk + (bid >> 3)) : bid;
  const int sn = pos / 49;
  const int rr = pos - sn * 49;
  const int py = rr / 7;
  const int px = rr - py * 7;
  const int c4 = threadIdx.x;

  const int yt = 2 * (sn * 7 + py);
  const int xt = N * 14 + 2 * (sn * 7 + px);
  const int    n  = perm[sn];           // original roi (output addressing)
  const int4   yi = tab[yt];
  const float4 yw = ((const float4*)tab)[yt + 1];
  const int4   xi = tab[xt];
  const float4 xw = ((const float4*)tab)[xt + 1];

  // force offsets into SGPRs (scalar base folding for the gathers)
  const int r0 = rfl(yi.x), r1 = rfl(yi.y), r2 = rfl(yi.z), r3 = rfl(yi.w);
  const int c0 = rfl(xi.x), c1 = rfl(xi.y), c2 = rfl(xi.z), c3 = rfl(xi.w);

  const vf4 gy0 = splat4(yw.x), fy0 = splat4(yw.y);
  const vf4 gy1 = splat4(yw.z), fy1 = splat4(yw.w);
  const vf4 gx0 = splat4(xw.x), fx0 = splat4(xw.y);
  const vf4 gx1 = splat4(xw.z), fx1 = splat4(xw.w);

  const char* __restrict__ imgb = (const char*)img;
  const int coff = c4 * 16;  // shared per-lane voffset

  // uniform dedup conditions (exact byte-offset equality)
  const bool c2e0 = (c2 == c0), c2e1 = (c2 == c1);
  const bool c3e1 = (c3 == c1), c3e2 = (c3 == c2);

  auto rowblend = [&](int rB, vf4& b0, vf4& b1) {
    const vf4 q0 = *(const vf4*)(imgb + (rB + c0) + coff);
    const vf4 q1 = *(const vf4*)(imgb + (rB + c1) + coff);
    vf4 q2, q3;
    if (c2e0)      q2 = q0;
    else if (c2e1) q2 = q1;
    else           q2 = *(const vf4*)(imgb + (rB + c2) + coff);
    if (c3e1)      q3 = q1;
    else if (c3e2) q3 = q2;
    else           q3 = *(const vf4*)(imgb + (rB + c3) + coff);
    b0 = q0 * gx0 + q1 * fx0;
    b1 = q2 * gx1 + q3 * fx1;
  };

  vf4 b00, b01, b10, b11, b20, b21, b30, b31;
  rowblend(r0, b00, b01);
  if (r1 == r0) { b10 = b00; b11 = b01; }
  else rowblend(r1, b10, b11);
  if (r2 == r0)      { b20 = b00; b21 = b01; }
  else if (r2 == r1) { b20 = b10; b21 = b11; }
  else rowblend(r2, b20, b21);
  if (r3 == r1)      { b30 = b10; b31 = b11; }
  else if (r3 == r2) { b30 = b20; b31 = b21; }
  else rowblend(r3, b30, b31);

  vf4 m = b00 * gy0 + b10 * fy0;
  vf4 v = b01 * gy0 + b11 * fy0;
  m = __builtin_elementwise_max(m, v);
  v = b20 * gy1 + b30 * fy1;
  m = __builtin_elementwise_max(m, v);
  v = b21 * gy1 + b31 * fy1;
  m = __builtin_elementwise_max(m, v);

  __builtin_nontemporal_store(m, (vf4*)out + ((size_t)n * 49 + rr) * 256 + c4);
}

// ---------------------------------------------------------------------------
// Fallback (R6 kernel, self-contained): used only if ws_size is too small.
// ---------------------------------------------------------------------------
__device__ __forceinline__ float rflf(float x) {
  union { float f; int i; } u;
  u.f = x;
  u.i = __builtin_amdgcn_readfirstlane(u.i);
  return u.f;
}

__global__ __launch_bounds__(256) void roi_pool_kernel(
    const float* __restrict__ img, const float* __restrict__ rois,
    const int* __restrict__ stride_p, float* __restrict__ out) {
  const int bid = blockIdx.x;
  const int chunk = gridDim.x >> 3;
  const int pos = ((gridDim.x & 7) == 0) ? ((bid & 7) * chunk + (bid >> 3)) : bid;
  const int n  = pos / 49;
  const int rr = pos - n * 49;
  const int py = rr / 7;
  const int px = rr - py * 7;
  const int c4 = threadIdx.x;

  const float s = (float)(*stride_p);
  const float by1 = rois[n * 4 + 0] / s / 50.0f;
  const float bx1 = rois[n * 4 + 1] / s / 64.0f;
  const float by2 = rois[n * 4 + 2] / s / 50.0f;
  const float bx2 = rois[n * 4 + 3] / s / 64.0f;
  const float stepy = (by2 - by1) * 49.0f / 13.0f;
  const float stepx = (bx2 - bx1) * 63.0f / 13.0f;

  const float ys0 = by1 * 49.0f + (float)(2 * py + 0) * stepy;
  const float ys1 = by1 * 49.0f + (float)(2 * py + 1) * stepy;
  const float xs0 = bx1 * 63.0f + (float)(2 * px + 0) * stepx;
  const float xs1 = bx1 * 63.0f + (float)(2 * px + 1) * stepx;
  const float vy0 = (ys0 >= 0.0f && ys0 <= 49.0f) ? 1.0f : 0.0f;
  const float vy1 = (ys1 >= 0.0f && ys1 <= 49.0f) ? 1.0f : 0.0f;
  const float vx0 = (xs0 >= 0.0f && xs0 <= 63.0f) ? 1.0f : 0.0f;
  const float vx1 = (xs1 >= 0.0f && xs1 <= 63.0f) ? 1.0f : 0.0f;
  const float yf0 = floorf(ys0), yf1 = floorf(ys1);
  const float xf0 = floorf(xs0), xf1 = floorf(xs1);
  const float wy0 = ys0 - yf0, wy1 = ys1 - yf1;
  const float wx0 = xs0 - xf0, wx1 = xs1 - xf1;
  const int r0i = min(max((int)yf0, 0), 49);
  const int r2i = min(max((int)yf1, 0), 49);
  const int c0i = min(max((int)xf0, 0), 63);
  const int c2i = min(max((int)xf1, 0), 63);
  const int r0 = rfl(r0i), r1 = rfl(min(r0i + 1, 49));
  const int r2 = rfl(r2i), r3 = rfl(min(r2i + 1, 49));
  const int c0 = rfl(c0i), c1 = rfl(min(c0i + 1, 63));
  const int c2 = rfl(c2i), c3 = rfl(min(c2i + 1, 63));
  const vf4 gy0 = splat4(rflf((1.0f - wy0) * vy0));
  const vf4 fy0 = splat4(rflf(wy0 * vy0));
  const vf4 gy1 = splat4(rflf((1.0f - wy1) * vy1));
  const vf4 fy1 = splat4(rflf(wy1 * vy1));
  const vf4 gx0 = splat4(rflf((1.0f - wx0) * vx0));
  const vf4 fx0 = splat4(rflf(wx0 * vx0));
  const vf4 gx1 = splat4(rflf((1.0f - wx1) * vx1));
  const vf4 fx1 = splat4(rflf(wx1 * vx1));

  const vf4* __restrict__ img4 = (const vf4*)img;
  const bool c2e0 = (c2 == c0), c2e1 = (c2 == c1);
  const bool c3e1 = (c3 == c1), c3e2 = (c3 == c2);
  const int co0 = c0 * 256, co1 = c1 * 256, co2 = c2 * 256, co3 = c3 * 256;

  auto rowblend = [&](int r, vf4& b0, vf4& b1) {
    const vf4* rp = img4 + r * (64 * 256);
    const vf4 q0 = rp[co0 + c4];
    const vf4 q1 = rp[co1 + c4];
    vf4 q2, q3;
    if (c2e0)      q2 = q0;
    else if (c2e1) q2 = q1;
    else           q2 = rp[co2 + c4];
    if (c3e1)      q3 = q1;
    else if (c3e2) q3 = q2;
    else           q3 = rp[co3 + c4];
    b0 = q0 * gx0 + q1 * fx0;
    b1 = q2 * gx1 + q3 * fx1;
  };

  vf4 b00, b01, b10, b11, b20, b21, b30, b31;
  rowblend(r0, b00, b01);
  if (r1 == r0) { b10 = b00; b11 = b01; }
  else rowblend(r1, b10, b11);
  if (r2 == r0)      { b20 = b00; b21 = b01; }
  else if (r2 == r1) { b20 = b10; b21 = b11; }
  else rowblend(r2, b20, b21);
  if (r3 == r1)      { b30 = b10; b31 = b11; }
  else if (r3 == r2) { b30 = b20; b31 = b21; }
  else rowblend(r3, b30, b31);

  vf4 m = b00 * gy0 + b10 * fy0;
  vf4 v = b01 * gy0 + b11 * fy0;
  m = __builtin_elementwise_max(m, v);
  v = b20 * gy1 + b30 * fy1;
  m = __builtin_elementwise_max(m, v);
  v = b21 * gy1 + b31 * fy1;
  m = __builtin_elementwise_max(m, v);

  __builtin_nontemporal_store(m, (vf4*)out + (size_t)pos * 256 + c4);
}

}  // namespace

extern "C" void kernel_launch(void* const* d_in, const int* in_sizes, int n_in,
                              void* d_out, int out_size, void* d_ws, size_t ws_size,
                              hipStream_t stream) {
  const float* img      = (const float*)d_in[0];
  const float* rois     = (const float*)d_in[1];
  const int*   stride_p = (const int*)d_in[2];
  float*       out      = (float*)d_out;

  const int N = in_sizes[1] / 4;                     // 1000
  const size_t tab_bytes  = (size_t)N * 28 * 16;     // 28 int4s per roi
  const size_t perm_bytes = (size_t)((N + 63) & ~63) * sizeof(int);

  if (ws_size >= tab_bytes + perm_bytes && N <= 1024) {
    int4* tab  = (int4*)d_ws;
    int*  perm = (int*)((char*)d_ws + tab_bytes);
    roi_sort_kernel<<<1, 512, 0, stream>>>(rois, stride_p, perm, N);
    roi_setup_kernel<<<(N * 7 + 63) / 64, 64, 0, stream>>>(rois, stride_p, perm,
                                                           tab, N);
    roi_pool_tab<<<N * 49, 256, 0, stream>>>(img, tab, perm, N, out);
  } else {
    roi_pool_kernel<<<N * 49, 256, 0, stream>>>(img, rois, stride_p, out);
  }
}